// Round 9
// baseline (508.033 us; speedup 1.0000x reference)
//
#include <hip/hip_runtime.h>
#include <math.h>

#define HEADS 4
#define HID 64
#define HC 256
#define NEG_SLOPE 0.2f
#define GG 128

typedef __attribute__((ext_vector_type(8))) short short8;
typedef __attribute__((ext_vector_type(4))) float floatx4;
typedef unsigned short ush;

__device__ __forceinline__ ush f2bf(float f) {
  unsigned u = __float_as_uint(f);
  unsigned r = (u + 0x7FFFu + ((u >> 16) & 1u)) >> 16;  // RNE
  return (ush)r;
}
__device__ __forceinline__ float bf2f(ush h) {
  return __uint_as_float(((unsigned)h) << 16);
}

// ---------------- CSR build (counting sort by dst) ----------------
__global__ void hist_kernel(const int* __restrict__ ei, int* counts, int E, int n) {
  int i = blockIdx.x * 256 + threadIdx.x;
  if (i >= E + n) return;
  int d = (i < E) ? ei[E + i] : (i - E);
  atomicAdd(&counts[d], 1);
}

__global__ __launch_bounds__(256) void scan_pass1(const int* __restrict__ counts,
                                                  int* __restrict__ bsums, int n) {
  int t = threadIdx.x;
  int i0 = blockIdx.x * 1024 + t * 4;
  int s = 0;
  if (i0 + 3 < n) {
    int4 v = *(const int4*)&counts[i0];
    s = v.x + v.y + v.z + v.w;
  } else {
#pragma unroll
    for (int k = 0; k < 4; ++k)
      if (i0 + k < n) s += counts[i0 + k];
  }
#pragma unroll
  for (int o = 1; o < 64; o <<= 1) s += __shfl_xor(s, o, 64);
  __shared__ int ws[4];
  if ((t & 63) == 0) ws[t >> 6] = s;
  __syncthreads();
  if (t == 0) bsums[blockIdx.x] = ws[0] + ws[1] + ws[2] + ws[3];
}

__global__ __launch_bounds__(256) void scan_pass2(int* __restrict__ bsums,
                                                  int* __restrict__ row_ptr, int nb, int n) {
  __shared__ int sh[256];
  int t = threadIdx.x;
  int v = (t < nb) ? bsums[t] : 0;
  sh[t] = v;
  __syncthreads();
  for (int off = 1; off < 256; off <<= 1) {
    int u = (t >= off) ? sh[t - off] : 0;
    __syncthreads();
    sh[t] += u;
    __syncthreads();
  }
  if (t < nb) bsums[t] = sh[t] - v;  // exclusive
  if (t == 255) row_ptr[n] = sh[255];
}

__global__ __launch_bounds__(256) void scan_pass3(const int* __restrict__ counts,
                                                  const int* __restrict__ bsums,
                                                  int* __restrict__ row_ptr,
                                                  int* __restrict__ cursor, int n) {
  int t = threadIdx.x;
  int i0 = blockIdx.x * 1024 + t * 4;
  int c0 = 0, c1 = 0, c2 = 0, c3 = 0;
  bool full = (i0 + 3 < n);
  if (full) {
    int4 v = *(const int4*)&counts[i0];
    c0 = v.x; c1 = v.y; c2 = v.z; c3 = v.w;
  } else {
    if (i0 + 0 < n) c0 = counts[i0 + 0];
    if (i0 + 1 < n) c1 = counts[i0 + 1];
    if (i0 + 2 < n) c2 = counts[i0 + 2];
    if (i0 + 3 < n) c3 = counts[i0 + 3];
  }
  int ts = c0 + c1 + c2 + c3;
  __shared__ int sh[256];
  sh[t] = ts;
  __syncthreads();
  for (int off = 1; off < 256; off <<= 1) {
    int u = (t >= off) ? sh[t - off] : 0;
    __syncthreads();
    sh[t] += u;
    __syncthreads();
  }
  int run = bsums[blockIdx.x] + sh[t] - ts;
  int r0 = run, r1 = run + c0, r2 = r1 + c1, r3 = r2 + c2;
  if (full) {
    *(int4*)&row_ptr[i0] = make_int4(r0, r1, r2, r3);
    *(int4*)&cursor[i0] = make_int4(r0, r1, r2, r3);
  } else {
    if (i0 + 0 < n) { row_ptr[i0 + 0] = r0; cursor[i0 + 0] = r0; }
    if (i0 + 1 < n) { row_ptr[i0 + 1] = r1; cursor[i0 + 1] = r1; }
    if (i0 + 2 < n) { row_ptr[i0 + 2] = r2; cursor[i0 + 2] = r2; }
    if (i0 + 3 < n) { row_ptr[i0 + 3] = r3; cursor[i0 + 3] = r3; }
  }
}

__global__ void scatter_kernel(const int* __restrict__ ei, int* cursor, int* srcs, int E, int n) {
  int i = blockIdx.x * 256 + threadIdx.x;
  if (i >= E + n) return;
  int s, d;
  if (i < E) { s = ei[i]; d = ei[E + i]; }
  else       { s = i - E; d = s; }
  int pos = atomicAdd(&cursor[d], 1);
  srcs[pos] = s;
}

// ---------------- both B matrices: fp32 [256,256] -> bf16 hi/lo TRANSPOSED [n][k] ----------------
__global__ void convertB_kernel(const float* __restrict__ W1, const float* __restrict__ W2,
                                ush* __restrict__ Bth1, ush* __restrict__ Btl1,
                                ush* __restrict__ Bth2, ush* __restrict__ Btl2) {
  int k = blockIdx.x, n = threadIdx.x;
  const float* B = blockIdx.y ? W2 : W1;
  ush* th = blockIdx.y ? Bth2 : Bth1;
  ush* tl = blockIdx.y ? Btl2 : Btl1;
  float v = B[k * HC + n];
  ush h = f2bf(v);
  ush l = f2bf(v - bf2f(h));
  th[n * HC + k] = h;
  tl[n * HC + k] = l;
}

__device__ __forceinline__ void cvt4(float4 v, ushort4* h, ushort4* l) {
  ushort4 hh = make_ushort4(f2bf(v.x), f2bf(v.y), f2bf(v.z), f2bf(v.w));
  *h = hh;
  *l = make_ushort4(f2bf(v.x - bf2f(hh.x)), f2bf(v.y - bf2f(hh.y)),
                    f2bf(v.z - bf2f(hh.z)), f2bf(v.w - bf2f(hh.w)));
}

// ---------------- bf16-split MFMA GEMM (128x128, reg-prefetched K-loop) ----------------
// A input: either pre-split (Ah,Al) bf16, or raw fp32 (Axf != null; converted in staging).
// grid (2, ceil(M/128)), block 256 (4 waves, 2x2 of 64x64)
#define LDA 40  // padded k-stride in shorts (80B)
__global__ __launch_bounds__(256) void gemm_kernel(
    const float* __restrict__ Axf,
    const ush* __restrict__ Ah, const ush* __restrict__ Al,
    const ush* __restrict__ Bth, const ush* __restrict__ Btl,
    const float* __restrict__ att_src, const float* __restrict__ att_dst,
    ush* __restrict__ Cb, float* __restrict__ asrc_o, float* __restrict__ adst_o, int M) {
  __shared__ ush sAh[128 * LDA];
  __shared__ ush sAl[128 * LDA];
  __shared__ ush sBh[128 * LDA];
  __shared__ ush sBl[128 * LDA];

  int t = threadIdx.x;
  int lane = t & 63, wave = t >> 6;
  int wm = wave >> 1, wn = wave & 1;
  int q = lane >> 4, mrow = lane & 15;
  int r0 = blockIdx.y * 128;
  int c0 = blockIdx.x * 128;
  const int4 zero4 = make_int4(0, 0, 0, 0);
  const float4 zf4 = make_float4(0.f, 0.f, 0.f, 0.f);
  bool f32 = (Axf != nullptr);

  // staging tasks: 512 (row,seg8) pairs per array -> thread does t and t+256
  int row0 = t >> 2, seg0 = t & 3;
  int row1 = (t + 256) >> 2, seg1 = (t + 256) & 3;
  bool v0 = (r0 + row0) < M, v1 = (r0 + row1) < M;

  const ush* Ag0 = Ah + (size_t)(r0 + row0) * HC + seg0 * 8;
  const ush* Ag1 = Ah + (size_t)(r0 + row1) * HC + seg1 * 8;
  const ush* Al0 = Al + (size_t)(r0 + row0) * HC + seg0 * 8;
  const ush* Al1 = Al + (size_t)(r0 + row1) * HC + seg1 * 8;
  const float* X0 = Axf + (size_t)(r0 + row0) * HC + seg0 * 8;
  const float* X1 = Axf + (size_t)(r0 + row1) * HC + seg1 * 8;
  const ush* Bg0 = Bth + (size_t)(c0 + row0) * HC + seg0 * 8;
  const ush* Bg1 = Bth + (size_t)(c0 + row1) * HC + seg1 * 8;
  const ush* Bl0 = Btl + (size_t)(c0 + row0) * HC + seg0 * 8;
  const ush* Bl1 = Btl + (size_t)(c0 + row1) * HC + seg1 * 8;

  int4 pAh0, pAh1, pAl0, pAl1, pBh0, pBh1, pBl0, pBl1;
  float4 pX0a, pX0b, pX1a, pX1b;
  // prefetch k0 = 0
  if (f32) {
    pX0a = v0 ? *(const float4*)(X0) : zf4;
    pX0b = v0 ? *(const float4*)(X0 + 4) : zf4;
    pX1a = v1 ? *(const float4*)(X1) : zf4;
    pX1b = v1 ? *(const float4*)(X1 + 4) : zf4;
  } else {
    pAh0 = v0 ? *(const int4*)(Ag0) : zero4;
    pAh1 = v1 ? *(const int4*)(Ag1) : zero4;
    pAl0 = v0 ? *(const int4*)(Al0) : zero4;
    pAl1 = v1 ? *(const int4*)(Al1) : zero4;
  }
  pBh0 = *(const int4*)(Bg0);
  pBh1 = *(const int4*)(Bg1);
  pBl0 = *(const int4*)(Bl0);
  pBl1 = *(const int4*)(Bl1);

  floatx4 acc[4][4];
#pragma unroll
  for (int i = 0; i < 4; ++i)
#pragma unroll
    for (int j = 0; j < 4; ++j) acc[i][j] = (floatx4)(0.0f);

  for (int k0 = 0; k0 < HC; k0 += 32) {
    // write prefetched tile to LDS
    if (f32) {
      ushort4 h, l;
      cvt4(pX0a, &h, &l);
      *(ushort4*)&sAh[row0 * LDA + seg0 * 8] = h;
      *(ushort4*)&sAl[row0 * LDA + seg0 * 8] = l;
      cvt4(pX0b, &h, &l);
      *(ushort4*)&sAh[row0 * LDA + seg0 * 8 + 4] = h;
      *(ushort4*)&sAl[row0 * LDA + seg0 * 8 + 4] = l;
      cvt4(pX1a, &h, &l);
      *(ushort4*)&sAh[row1 * LDA + seg1 * 8] = h;
      *(ushort4*)&sAl[row1 * LDA + seg1 * 8] = l;
      cvt4(pX1b, &h, &l);
      *(ushort4*)&sAh[row1 * LDA + seg1 * 8 + 4] = h;
      *(ushort4*)&sAl[row1 * LDA + seg1 * 8 + 4] = l;
    } else {
      *(int4*)&sAh[row0 * LDA + seg0 * 8] = pAh0;
      *(int4*)&sAh[row1 * LDA + seg1 * 8] = pAh1;
      *(int4*)&sAl[row0 * LDA + seg0 * 8] = pAl0;
      *(int4*)&sAl[row1 * LDA + seg1 * 8] = pAl1;
    }
    *(int4*)&sBh[row0 * LDA + seg0 * 8] = pBh0;
    *(int4*)&sBh[row1 * LDA + seg1 * 8] = pBh1;
    *(int4*)&sBl[row0 * LDA + seg0 * 8] = pBl0;
    *(int4*)&sBl[row1 * LDA + seg1 * 8] = pBl1;
    __syncthreads();

    // issue next iteration's global loads (latency overlaps MFMA phase)
    int kn = k0 + 32;
    if (kn < HC) {
      if (f32) {
        pX0a = v0 ? *(const float4*)(X0 + kn) : zf4;
        pX0b = v0 ? *(const float4*)(X0 + kn + 4) : zf4;
        pX1a = v1 ? *(const float4*)(X1 + kn) : zf4;
        pX1b = v1 ? *(const float4*)(X1 + kn + 4) : zf4;
      } else {
        pAh0 = v0 ? *(const int4*)(Ag0 + kn) : zero4;
        pAh1 = v1 ? *(const int4*)(Ag1 + kn) : zero4;
        pAl0 = v0 ? *(const int4*)(Al0 + kn) : zero4;
        pAl1 = v1 ? *(const int4*)(Al1 + kn) : zero4;
      }
      pBh0 = *(const int4*)(Bg0 + kn);
      pBh1 = *(const int4*)(Bg1 + kn);
      pBl0 = *(const int4*)(Bl0 + kn);
      pBl1 = *(const int4*)(Bl1 + kn);
    }

    short8 ah[4], al[4], bh[4], bl[4];
#pragma unroll
    for (int i = 0; i < 4; ++i) {
      int ar = (wm * 64 + i * 16 + mrow) * LDA + q * 8;
      int br = (wn * 64 + i * 16 + mrow) * LDA + q * 8;
      ah[i] = *(short8*)&sAh[ar];
      al[i] = *(short8*)&sAl[ar];
      bh[i] = *(short8*)&sBh[br];
      bl[i] = *(short8*)&sBl[br];
    }
#pragma unroll
    for (int i = 0; i < 4; ++i)
#pragma unroll
      for (int j = 0; j < 4; ++j) {
        acc[i][j] = __builtin_amdgcn_mfma_f32_16x16x32_bf16(ah[i], bh[j], acc[i][j], 0, 0, 0);
        acc[i][j] = __builtin_amdgcn_mfma_f32_16x16x32_bf16(ah[i], bl[j], acc[i][j], 0, 0, 0);
        acc[i][j] = __builtin_amdgcn_mfma_f32_16x16x32_bf16(al[i], bh[j], acc[i][j], 0, 0, 0);
      }
    __syncthreads();
  }

  // ---- fused att: wave wn owns head hd's full 64-col stripe ----
  int hd = (c0 >> 6) + wn;
  float aS[4], aD[4];
#pragma unroll
  for (int j = 0; j < 4; ++j) {
    aS[j] = att_src[hd * 64 + j * 16 + mrow];
    aD[j] = att_dst[hd * 64 + j * 16 + mrow];
  }
#pragma unroll
  for (int i = 0; i < 4; ++i) {
#pragma unroll
    for (int r = 0; r < 4; ++r) {
      float ps = acc[i][0][r] * aS[0] + acc[i][1][r] * aS[1] +
                 acc[i][2][r] * aS[2] + acc[i][3][r] * aS[3];
      float pd = acc[i][0][r] * aD[0] + acc[i][1][r] * aD[1] +
                 acc[i][2][r] * aD[2] + acc[i][3][r] * aD[3];
#pragma unroll
      for (int o = 1; o < 16; o <<= 1) {
        ps += __shfl_xor(ps, o, 64);
        pd += __shfl_xor(pd, o, 64);
      }
      int grow = r0 + wm * 64 + i * 16 + q * 4 + r;
      if (mrow == 0 && grow < M) {
        asrc_o[grow * HEADS + hd] = ps;
        adst_o[grow * HEADS + hd] = pd;
      }
    }
  }

  // ---- bf16 C store (C/D layout: col=lane&15, row=(lane>>4)*4+reg) ----
#pragma unroll
  for (int i = 0; i < 4; ++i) {
#pragma unroll
    for (int j = 0; j < 4; ++j) {
      int col = c0 + wn * 64 + j * 16 + mrow;
#pragma unroll
      for (int r = 0; r < 4; ++r) {
        int grow = r0 + wm * 64 + i * 16 + q * 4 + r;
        if (grow < M) Cb[(size_t)grow * HC + col] = f2bf(acc[i][j][r]);
      }
    }
  }
}

__device__ __forceinline__ float lrelu(float x) { return x > 0.f ? x : NEG_SLOPE * x; }

// ---------------- segment softmax + aggregation: ONE WAVE PER NODE ----------------
// Gather phase: half-wave per edge (16B/lane, 2 edges per wave-iteration).
__global__ __launch_bounds__(256) void aggregate_kernel(
    const ush* __restrict__ hbf, const float* __restrict__ asrc,
    const float* __restrict__ adst, const int* __restrict__ row_ptr,
    const int* __restrict__ srcs, const float* __restrict__ bias,
    float* __restrict__ outf, ush* __restrict__ outh, ush* __restrict__ outl, int N) {
  __shared__ float s_alpha[4][64 * 4];
  __shared__ int s_src[4][64];

  int wave = threadIdx.x >> 6;
  int lane = threadIdx.x & 63;
  int node = blockIdx.x * 4 + wave;
  if (node >= N) return;

  int begin = row_ptr[node];
  int end = row_ptr[node + 1];
  int deg = end - begin;
  int nb = deg < 64 ? deg : 64;

  const float4* asrc4 = (const float4*)asrc;
  float4 ad = ((const float4*)adst)[node];

  const float NEGINF = -3.402823466e38f;
  int s0 = 0;
  float4 e0 = make_float4(NEGINF, NEGINF, NEGINF, NEGINF);
  if (lane < nb) {
    s0 = srcs[begin + lane];
    float4 a = asrc4[s0];
    e0.x = lrelu(a.x + ad.x);
    e0.y = lrelu(a.y + ad.y);
    e0.z = lrelu(a.z + ad.z);
    e0.w = lrelu(a.w + ad.w);
  }
  float m0 = e0.x, m1 = e0.y, m2 = e0.z, m3 = e0.w;
  for (int base = 64; base < deg; base += 64) {
    int idx = base + lane;
    if (idx < deg) {
      int s = srcs[begin + idx];
      float4 a = asrc4[s];
      m0 = fmaxf(m0, lrelu(a.x + ad.x));
      m1 = fmaxf(m1, lrelu(a.y + ad.y));
      m2 = fmaxf(m2, lrelu(a.z + ad.z));
      m3 = fmaxf(m3, lrelu(a.w + ad.w));
    }
  }
#pragma unroll
  for (int o = 1; o < 64; o <<= 1) {
    m0 = fmaxf(m0, __shfl_xor(m0, o, 64));
    m1 = fmaxf(m1, __shfl_xor(m1, o, 64));
    m2 = fmaxf(m2, __shfl_xor(m2, o, 64));
    m3 = fmaxf(m3, __shfl_xor(m3, o, 64));
  }
  float ex0 = (lane < nb) ? __expf(e0.x - m0) : 0.f;
  float ex1 = (lane < nb) ? __expf(e0.y - m1) : 0.f;
  float ex2 = (lane < nb) ? __expf(e0.z - m2) : 0.f;
  float ex3 = (lane < nb) ? __expf(e0.w - m3) : 0.f;
  float d0 = ex0, d1 = ex1, d2 = ex2, d3 = ex3;
  for (int base = 64; base < deg; base += 64) {
    int idx = base + lane;
    if (idx < deg) {
      int s = srcs[begin + idx];
      float4 a = asrc4[s];
      d0 += __expf(lrelu(a.x + ad.x) - m0);
      d1 += __expf(lrelu(a.y + ad.y) - m1);
      d2 += __expf(lrelu(a.z + ad.z) - m2);
      d3 += __expf(lrelu(a.w + ad.w) - m3);
    }
  }
#pragma unroll
  for (int o = 1; o < 64; o <<= 1) {
    d0 += __shfl_xor(d0, o, 64);
    d1 += __shfl_xor(d1, o, 64);
    d2 += __shfl_xor(d2, o, 64);
    d3 += __shfl_xor(d3, o, 64);
  }
  float r0 = 1.0f / (d0 + 1e-16f);
  float r1 = 1.0f / (d1 + 1e-16f);
  float r2 = 1.0f / (d2 + 1e-16f);
  float r3 = 1.0f / (d3 + 1e-16f);

  *(float4*)&s_alpha[wave][lane * 4] = make_float4(ex0 * r0, ex1 * r1, ex2 * r2, ex3 * r3);
  s_src[wave][lane] = s0;

  // ---- gather: half-wave per edge; lane owns 8 channels (16B) ----
  int half = lane >> 5;   // 0: even edges, 1: odd edges
  int hl = lane & 31;     // channel block: channels [hl*8, hl*8+8)
  int headh = hl >> 3;    // head of those channels
  float mh = (headh == 0) ? m0 : (headh == 1) ? m1 : (headh == 2) ? m2 : m3;
  float rdh = (headh == 0) ? r0 : (headh == 1) ? r1 : (headh == 2) ? r2 : r3;
  float adh = (headh == 0) ? ad.x : (headh == 1) ? ad.y : (headh == 2) ? ad.z : ad.w;

  const short8* hb8 = (const short8*)hbf;  // row = 32 x short8
  float acc[8];
#pragma unroll
  for (int k = 0; k < 8; ++k) acc[k] = 0.f;

  for (int i = half; i < nb; i += 2) {
    int s = s_src[wave][i];
    float a = s_alpha[wave][i * 4 + headh];
    short8 u = hb8[(size_t)s * 32 + hl];
#pragma unroll
    for (int k = 0; k < 8; ++k) acc[k] += a * bf2f((ush)u[k]);
  }
  // rare: edges beyond 64 — recompute alpha on the fly
  for (int i2 = 64 + half; i2 < deg; i2 += 2) {
    int s = srcs[begin + i2];
    float ash = asrc[s * HEADS + headh];
    float a = __expf(lrelu(ash + adh) - mh) * rdh;
    short8 u = hb8[(size_t)s * 32 + hl];
#pragma unroll
    for (int k = 0; k < 8; ++k) acc[k] += a * bf2f((ush)u[k]);
  }

  // combine even/odd halves
#pragma unroll
  for (int k = 0; k < 8; ++k) acc[k] += __shfl_xor(acc[k], 32, 64);

  if (half == 0) {
    float4 bv0 = ((const float4*)bias)[hl * 2];
    float4 bv1 = ((const float4*)bias)[hl * 2 + 1];
    float o0 = fmaxf(acc[0] + bv0.x, 0.f);
    float o1 = fmaxf(acc[1] + bv0.y, 0.f);
    float o2 = fmaxf(acc[2] + bv0.z, 0.f);
    float o3 = fmaxf(acc[3] + bv0.w, 0.f);
    float o4 = fmaxf(acc[4] + bv1.x, 0.f);
    float o5 = fmaxf(acc[5] + bv1.y, 0.f);
    float o6 = fmaxf(acc[6] + bv1.z, 0.f);
    float o7 = fmaxf(acc[7] + bv1.w, 0.f);
    if (outf) {
      ((float4*)outf)[(size_t)node * 64 + hl * 2] = make_float4(o0, o1, o2, o3);
      ((float4*)outf)[(size_t)node * 64 + hl * 2 + 1] = make_float4(o4, o5, o6, o7);
    } else {
      ush h0 = f2bf(o0), h1 = f2bf(o1), h2 = f2bf(o2), h3 = f2bf(o3);
      ush h4 = f2bf(o4), h5 = f2bf(o5), h6 = f2bf(o6), h7 = f2bf(o7);
      short8 hv;
      hv[0] = (short)h0; hv[1] = (short)h1; hv[2] = (short)h2; hv[3] = (short)h3;
      hv[4] = (short)h4; hv[5] = (short)h5; hv[6] = (short)h6; hv[7] = (short)h7;
      *(short8*)&outh[(size_t)node * HC + hl * 8] = hv;
      if (outl) {
        short8 lv;
        lv[0] = (short)f2bf(o0 - bf2f(h0));
        lv[1] = (short)f2bf(o1 - bf2f(h1));
        lv[2] = (short)f2bf(o2 - bf2f(h2));
        lv[3] = (short)f2bf(o3 - bf2f(h3));
        lv[4] = (short)f2bf(o4 - bf2f(h4));
        lv[5] = (short)f2bf(o5 - bf2f(h5));
        lv[6] = (short)f2bf(o6 - bf2f(h6));
        lv[7] = (short)f2bf(o7 - bf2f(h7));
        *(short8*)&outl[(size_t)node * HC + hl * 8] = lv;
      }
    }
  }
}

// ---------------- global mean pool (batch is sorted, input bf16), 4 partials per graph ----------------
__device__ __forceinline__ int lower_bound_i(const int* a, int n, int key) {
  int lo = 0, hi = n;
  while (lo < hi) {
    int mid = (lo + hi) >> 1;
    if (a[mid] < key) lo = mid + 1; else hi = mid;
  }
  return lo;
}

__global__ __launch_bounds__(256) void pool_kernel(const ush* __restrict__ h2,
                                                   const int* __restrict__ batch,
                                                   float* __restrict__ pws,
                                                   int* __restrict__ cnts, int n) {
  int g = blockIdx.x, part = blockIdx.y;
  int wave = threadIdx.x >> 6, lane = threadIdx.x & 63;
  int lo = lower_bound_i(batch, n, g);
  int hi = lower_bound_i(batch, n, g + 1);
  const ushort4* h4 = (const ushort4*)h2;
  float4 acc = make_float4(0.f, 0.f, 0.f, 0.f);
  for (int i = lo + part * 4 + wave; i < hi; i += 16) {
    ushort4 u = h4[(size_t)i * 64 + lane];
    acc.x += bf2f(u.x); acc.y += bf2f(u.y);
    acc.z += bf2f(u.z); acc.w += bf2f(u.w);
  }
  __shared__ float4 red[4][64];
  red[wave][lane] = acc;
  __syncthreads();
  if (wave == 0) {
    float4 a0 = red[0][lane], a1 = red[1][lane], a2 = red[2][lane], a3 = red[3][lane];
    float4 o;
    o.x = (a0.x + a1.x) + (a2.x + a3.x);
    o.y = (a0.y + a1.y) + (a2.y + a3.y);
    o.z = (a0.z + a1.z) + (a2.z + a3.z);
    o.w = (a0.w + a1.w) + (a2.w + a3.w);
    ((float4*)pws)[(size_t)(g * 4 + part) * 64 + lane] = o;
  }
  if (part == 0 && threadIdx.x == 0) cnts[g] = hi - lo;
}

// ---------------- combine partials + final linear [G,256]@[256,10] ----------------
__global__ void final_kernel(const float* __restrict__ pws, const int* __restrict__ cnts,
                             const float* __restrict__ Wf, const float* __restrict__ bf,
                             float* __restrict__ pooled_out, float* __restrict__ out) {
  int g = blockIdx.x, t = threadIdx.x;
  float s = pws[(size_t)(g * 4 + 0) * 256 + t] + pws[(size_t)(g * 4 + 1) * 256 + t] +
            pws[(size_t)(g * 4 + 2) * 256 + t] + pws[(size_t)(g * 4 + 3) * 256 + t];
  float inv = 1.0f / fmaxf((float)cnts[g], 1.0f);
  float pv = s * inv;
  pooled_out[g * HC + t] = pv;
  __shared__ float p[HC];
  p[t] = pv;
  __syncthreads();
  if (t < 10) {
    float acc = bf[t];
    for (int c = 0; c < HC; ++c) acc += p[c] * Wf[c * 10 + t];
    out[g * 10 + t] = acc;
  }
}

extern "C" void kernel_launch(void* const* d_in, const int* in_sizes, int n_in,
                              void* d_out, int out_size, void* d_ws, size_t ws_size,
                              hipStream_t stream) {
  const float* x    = (const float*)d_in[0];
  const int*   ei   = (const int*)d_in[1];
  const int*   batch = (const int*)d_in[3];
  const float* W1   = (const float*)d_in[4];
  const float* as1  = (const float*)d_in[5];
  const float* ad1  = (const float*)d_in[6];
  const float* b1   = (const float*)d_in[7];
  const float* W2   = (const float*)d_in[8];
  const float* as2  = (const float*)d_in[9];
  const float* ad2  = (const float*)d_in[10];
  const float* b2   = (const float*)d_in[11];
  const float* Wf   = (const float*)d_in[12];
  const float* bf   = (const float*)d_in[13];
  float* out = (float*)d_out;

  const int N = in_sizes[0] / HC;  // 50000
  const int E = in_sizes[1] / 2;   // 800000

  // workspace layout (256B-aligned chunks)
  char* base = (char*)d_ws;
  size_t off = 0;
  auto alloc = [&](size_t bytes) {
    char* p = base + off;
    off = (off + bytes + 255) & ~(size_t)255;
    return p;
  };
  ush* xh = (ush*)alloc((size_t)N * HC * 2);   // bf16 hi (agg1 out / gemm2 A / agg2 out)
  ush* xl = (ush*)alloc((size_t)N * HC * 2);   // bf16 lo
  ush* hbf = (ush*)alloc((size_t)N * HC * 2);  // bf16 projected features
  float* asrc = (float*)alloc((size_t)N * HEADS * 4);
  float* adst = (float*)alloc((size_t)N * HEADS * 4);
  int* counts = (int*)alloc((size_t)N * 4);
  int* row_ptr = (int*)alloc((size_t)(N + 1) * 4);
  int* cursor = (int*)alloc((size_t)N * 4);
  int* srcs = (int*)alloc((size_t)(E + N) * 4);
  int* bsums = (int*)alloc(((N + 1023) / 1024) * 4);
  ush* Bth1 = (ush*)alloc((size_t)HC * HC * 2);
  ush* Btl1 = (ush*)alloc((size_t)HC * HC * 2);
  ush* Bth2 = (ush*)alloc((size_t)HC * HC * 2);
  ush* Btl2 = (ush*)alloc((size_t)HC * HC * 2);
  float* pws = (float*)alloc((size_t)GG * 4 * HC * 4);
  int* cnts = (int*)alloc((size_t)GG * 4);

  int nb = (N + 1023) / 1024;

  // CSR build
  hipMemsetAsync(counts, 0, (size_t)N * 4, stream);
  hist_kernel<<<(E + N + 255) / 256, 256, 0, stream>>>(ei, counts, E, N);
  scan_pass1<<<nb, 256, 0, stream>>>(counts, bsums, N);
  scan_pass2<<<1, 256, 0, stream>>>(bsums, row_ptr, nb, N);
  scan_pass3<<<nb, 256, 0, stream>>>(counts, bsums, row_ptr, cursor, N);
  scatter_kernel<<<(E + N + 255) / 256, 256, 0, stream>>>(ei, cursor, srcs, E, N);

  // weight prep
  dim3 cbgrid(HC, 2);
  convertB_kernel<<<cbgrid, HC, 0, stream>>>(W1, W2, Bth1, Btl1, Bth2, Btl2);

  dim3 ggrid(2, (N + 127) / 128);
  int agg_blocks = (N + 3) / 4;

  // layer 1: GEMM stages directly from fp32 x (split fused into staging)
  gemm_kernel<<<ggrid, 256, 0, stream>>>(x, nullptr, nullptr, Bth1, Btl1, as1, ad1,
                                         hbf, asrc, adst, N);
  aggregate_kernel<<<agg_blocks, 256, 0, stream>>>(hbf, asrc, adst, row_ptr, srcs, b1,
                                                   nullptr, xh, xl, N);

  // layer 2 (pre-split A from aggregate 1; aggregate emits bf16 for pooling)
  gemm_kernel<<<ggrid, 256, 0, stream>>>(nullptr, xh, xl, Bth2, Btl2, as2, ad2,
                                         hbf, asrc, adst, N);
  aggregate_kernel<<<agg_blocks, 256, 0, stream>>>(hbf, asrc, adst, row_ptr, srcs, b2,
                                                   nullptr, xh, nullptr, N);

  // pooling + classifier
  dim3 pgrid(GG, 4);
  pool_kernel<<<pgrid, 256, 0, stream>>>(xh, batch, pws, cnts, N);
  final_kernel<<<GG, 256, 0, stream>>>(pws, cnts, Wf, bf, out + GG * 10, out);
}

// Round 10
// 473.586 us; speedup vs baseline: 1.0727x; 1.0727x over previous
//
#include <hip/hip_runtime.h>
#include <math.h>

#define HEADS 4
#define HID 64
#define HC 256
#define NEG_SLOPE 0.2f
#define GG 128

typedef __attribute__((ext_vector_type(8))) short short8;
typedef __attribute__((ext_vector_type(4))) float floatx4;
typedef unsigned short ush;

__device__ __forceinline__ ush f2bf(float f) {
  unsigned u = __float_as_uint(f);
  unsigned r = (u + 0x7FFFu + ((u >> 16) & 1u)) >> 16;  // RNE
  return (ush)r;
}
__device__ __forceinline__ float bf2f(ush h) {
  return __uint_as_float(((unsigned)h) << 16);
}

// ---------------- CSR build (counting sort by dst) ----------------
__global__ void hist_kernel(const int* __restrict__ ei, int* counts, int E, int n) {
  int i = blockIdx.x * 256 + threadIdx.x;
  if (i >= E + n) return;
  int d = (i < E) ? ei[E + i] : (i - E);
  atomicAdd(&counts[d], 1);
}

__global__ __launch_bounds__(256) void scan_pass1(const int* __restrict__ counts,
                                                  int* __restrict__ bsums, int n) {
  int t = threadIdx.x;
  int i0 = blockIdx.x * 1024 + t * 4;
  int s = 0;
  if (i0 + 3 < n) {
    int4 v = *(const int4*)&counts[i0];
    s = v.x + v.y + v.z + v.w;
  } else {
#pragma unroll
    for (int k = 0; k < 4; ++k)
      if (i0 + k < n) s += counts[i0 + k];
  }
#pragma unroll
  for (int o = 1; o < 64; o <<= 1) s += __shfl_xor(s, o, 64);
  __shared__ int ws[4];
  if ((t & 63) == 0) ws[t >> 6] = s;
  __syncthreads();
  if (t == 0) bsums[blockIdx.x] = ws[0] + ws[1] + ws[2] + ws[3];
}

__global__ __launch_bounds__(256) void scan_pass2(int* __restrict__ bsums,
                                                  int* __restrict__ row_ptr, int nb, int n) {
  __shared__ int sh[256];
  int t = threadIdx.x;
  int v = (t < nb) ? bsums[t] : 0;
  sh[t] = v;
  __syncthreads();
  for (int off = 1; off < 256; off <<= 1) {
    int u = (t >= off) ? sh[t - off] : 0;
    __syncthreads();
    sh[t] += u;
    __syncthreads();
  }
  if (t < nb) bsums[t] = sh[t] - v;  // exclusive
  if (t == 255) row_ptr[n] = sh[255];
}

__global__ __launch_bounds__(256) void scan_pass3(const int* __restrict__ counts,
                                                  const int* __restrict__ bsums,
                                                  int* __restrict__ row_ptr,
                                                  int* __restrict__ cursor, int n) {
  int t = threadIdx.x;
  int i0 = blockIdx.x * 1024 + t * 4;
  int c0 = 0, c1 = 0, c2 = 0, c3 = 0;
  bool full = (i0 + 3 < n);
  if (full) {
    int4 v = *(const int4*)&counts[i0];
    c0 = v.x; c1 = v.y; c2 = v.z; c3 = v.w;
  } else {
    if (i0 + 0 < n) c0 = counts[i0 + 0];
    if (i0 + 1 < n) c1 = counts[i0 + 1];
    if (i0 + 2 < n) c2 = counts[i0 + 2];
    if (i0 + 3 < n) c3 = counts[i0 + 3];
  }
  int ts = c0 + c1 + c2 + c3;
  __shared__ int sh[256];
  sh[t] = ts;
  __syncthreads();
  for (int off = 1; off < 256; off <<= 1) {
    int u = (t >= off) ? sh[t - off] : 0;
    __syncthreads();
    sh[t] += u;
    __syncthreads();
  }
  int run = bsums[blockIdx.x] + sh[t] - ts;
  int r0 = run, r1 = run + c0, r2 = r1 + c1, r3 = r2 + c2;
  if (full) {
    *(int4*)&row_ptr[i0] = make_int4(r0, r1, r2, r3);
    *(int4*)&cursor[i0] = make_int4(r0, r1, r2, r3);
  } else {
    if (i0 + 0 < n) { row_ptr[i0 + 0] = r0; cursor[i0 + 0] = r0; }
    if (i0 + 1 < n) { row_ptr[i0 + 1] = r1; cursor[i0 + 1] = r1; }
    if (i0 + 2 < n) { row_ptr[i0 + 2] = r2; cursor[i0 + 2] = r2; }
    if (i0 + 3 < n) { row_ptr[i0 + 3] = r3; cursor[i0 + 3] = r3; }
  }
}

__global__ void scatter_kernel(const int* __restrict__ ei, int* cursor, int* srcs, int E, int n) {
  int i = blockIdx.x * 256 + threadIdx.x;
  if (i >= E + n) return;
  int s, d;
  if (i < E) { s = ei[i]; d = ei[E + i]; }
  else       { s = i - E; d = s; }
  int pos = atomicAdd(&cursor[d], 1);
  srcs[pos] = s;
}

// ---------------- fp32 -> bf16 hi/lo split (elementwise) ----------------
__global__ __launch_bounds__(256) void splitA_kernel(const float* __restrict__ A,
                                                     ush* __restrict__ Ah,
                                                     ush* __restrict__ Al, int total) {
  int i0 = (blockIdx.x * 256 + threadIdx.x) * 4;
  if (i0 + 3 < total) {
    float4 v = *(const float4*)&A[i0];
    ushort4 h = make_ushort4(f2bf(v.x), f2bf(v.y), f2bf(v.z), f2bf(v.w));
    ushort4 l = make_ushort4(f2bf(v.x - bf2f(h.x)), f2bf(v.y - bf2f(h.y)),
                             f2bf(v.z - bf2f(h.z)), f2bf(v.w - bf2f(h.w)));
    *(ushort4*)&Ah[i0] = h;
    *(ushort4*)&Al[i0] = l;
  } else {
    for (int k = 0; k < 4 && i0 + k < total; ++k) {
      float v = A[i0 + k];
      ush h = f2bf(v);
      Ah[i0 + k] = h;
      Al[i0 + k] = f2bf(v - bf2f(h));
    }
  }
}

// ---------------- both B matrices: fp32 [256,256] -> bf16 hi/lo TRANSPOSED [n][k] ----------------
__global__ void convertB_kernel(const float* __restrict__ W1, const float* __restrict__ W2,
                                ush* __restrict__ Bth1, ush* __restrict__ Btl1,
                                ush* __restrict__ Bth2, ush* __restrict__ Btl2) {
  int k = blockIdx.x, n = threadIdx.x;
  const float* B = blockIdx.y ? W2 : W1;
  ush* th = blockIdx.y ? Bth2 : Bth1;
  ush* tl = blockIdx.y ? Btl2 : Btl1;
  float v = B[k * HC + n];
  ush h = f2bf(v);
  ush l = f2bf(v - bf2f(h));
  th[n * HC + k] = h;
  tl[n * HC + k] = l;
}

// ---------------- bf16-split MFMA GEMM (128x128, reg-prefetched K-loop) ----------------
// grid (2, ceil(M/128)), block 256 (4 waves, 2x2 of 64x64) — R8-proven shape.
#define LDA 40  // padded k-stride in shorts (80B)
__global__ __launch_bounds__(256) void gemm_kernel(
    const ush* __restrict__ Ah, const ush* __restrict__ Al,
    const ush* __restrict__ Bth, const ush* __restrict__ Btl,
    const float* __restrict__ att_src, const float* __restrict__ att_dst,
    ush* __restrict__ Cb, float* __restrict__ asrc_o, float* __restrict__ adst_o, int M) {
  __shared__ ush sAh[128 * LDA];
  __shared__ ush sAl[128 * LDA];
  __shared__ ush sBh[128 * LDA];
  __shared__ ush sBl[128 * LDA];

  int t = threadIdx.x;
  int lane = t & 63, wave = t >> 6;
  int wm = wave >> 1, wn = wave & 1;
  int q = lane >> 4, mrow = lane & 15;
  int r0 = blockIdx.y * 128;
  int c0 = blockIdx.x * 128;
  const int4 zero4 = make_int4(0, 0, 0, 0);

  // staging tasks: 512 (row,seg8) pairs per array -> thread does t and t+256
  int row0 = t >> 2, seg0 = t & 3;
  int row1 = (t + 256) >> 2, seg1 = (t + 256) & 3;
  bool v0 = (r0 + row0) < M, v1 = (r0 + row1) < M;

  const ush* Ag0 = Ah + (size_t)(r0 + row0) * HC + seg0 * 8;
  const ush* Ag1 = Ah + (size_t)(r0 + row1) * HC + seg1 * 8;
  const ush* Al0 = Al + (size_t)(r0 + row0) * HC + seg0 * 8;
  const ush* Al1 = Al + (size_t)(r0 + row1) * HC + seg1 * 8;
  const ush* Bg0 = Bth + (size_t)(c0 + row0) * HC + seg0 * 8;
  const ush* Bg1 = Bth + (size_t)(c0 + row1) * HC + seg1 * 8;
  const ush* Bl0 = Btl + (size_t)(c0 + row0) * HC + seg0 * 8;
  const ush* Bl1 = Btl + (size_t)(c0 + row1) * HC + seg1 * 8;

  int4 pAh0, pAh1, pAl0, pAl1, pBh0, pBh1, pBl0, pBl1;
  // prefetch k0 = 0
  pAh0 = v0 ? *(const int4*)(Ag0) : zero4;
  pAh1 = v1 ? *(const int4*)(Ag1) : zero4;
  pAl0 = v0 ? *(const int4*)(Al0) : zero4;
  pAl1 = v1 ? *(const int4*)(Al1) : zero4;
  pBh0 = *(const int4*)(Bg0);
  pBh1 = *(const int4*)(Bg1);
  pBl0 = *(const int4*)(Bl0);
  pBl1 = *(const int4*)(Bl1);

  floatx4 acc[4][4];
#pragma unroll
  for (int i = 0; i < 4; ++i)
#pragma unroll
    for (int j = 0; j < 4; ++j) acc[i][j] = (floatx4)(0.0f);

  for (int k0 = 0; k0 < HC; k0 += 32) {
    // write prefetched tile to LDS
    *(int4*)&sAh[row0 * LDA + seg0 * 8] = pAh0;
    *(int4*)&sAh[row1 * LDA + seg1 * 8] = pAh1;
    *(int4*)&sAl[row0 * LDA + seg0 * 8] = pAl0;
    *(int4*)&sAl[row1 * LDA + seg1 * 8] = pAl1;
    *(int4*)&sBh[row0 * LDA + seg0 * 8] = pBh0;
    *(int4*)&sBh[row1 * LDA + seg1 * 8] = pBh1;
    *(int4*)&sBl[row0 * LDA + seg0 * 8] = pBl0;
    *(int4*)&sBl[row1 * LDA + seg1 * 8] = pBl1;
    __syncthreads();

    // issue next iteration's global loads (latency overlaps MFMA phase)
    int kn = k0 + 32;
    if (kn < HC) {
      pAh0 = v0 ? *(const int4*)(Ag0 + kn) : zero4;
      pAh1 = v1 ? *(const int4*)(Ag1 + kn) : zero4;
      pAl0 = v0 ? *(const int4*)(Al0 + kn) : zero4;
      pAl1 = v1 ? *(const int4*)(Al1 + kn) : zero4;
      pBh0 = *(const int4*)(Bg0 + kn);
      pBh1 = *(const int4*)(Bg1 + kn);
      pBl0 = *(const int4*)(Bl0 + kn);
      pBl1 = *(const int4*)(Bl1 + kn);
    }

    short8 ah[4], al[4], bh[4], bl[4];
#pragma unroll
    for (int i = 0; i < 4; ++i) {
      int ar = (wm * 64 + i * 16 + mrow) * LDA + q * 8;
      int br = (wn * 64 + i * 16 + mrow) * LDA + q * 8;
      ah[i] = *(short8*)&sAh[ar];
      al[i] = *(short8*)&sAl[ar];
      bh[i] = *(short8*)&sBh[br];
      bl[i] = *(short8*)&sBl[br];
    }
#pragma unroll
    for (int i = 0; i < 4; ++i)
#pragma unroll
      for (int j = 0; j < 4; ++j) {
        acc[i][j] = __builtin_amdgcn_mfma_f32_16x16x32_bf16(ah[i], bh[j], acc[i][j], 0, 0, 0);
        acc[i][j] = __builtin_amdgcn_mfma_f32_16x16x32_bf16(ah[i], bl[j], acc[i][j], 0, 0, 0);
        acc[i][j] = __builtin_amdgcn_mfma_f32_16x16x32_bf16(al[i], bh[j], acc[i][j], 0, 0, 0);
      }
    __syncthreads();
  }

  // ---- fused att: wave wn owns head hd's full 64-col stripe ----
  int hd = (c0 >> 6) + wn;
  float aS[4], aD[4];
#pragma unroll
  for (int j = 0; j < 4; ++j) {
    aS[j] = att_src[hd * 64 + j * 16 + mrow];
    aD[j] = att_dst[hd * 64 + j * 16 + mrow];
  }
#pragma unroll
  for (int i = 0; i < 4; ++i) {
#pragma unroll
    for (int r = 0; r < 4; ++r) {
      float ps = acc[i][0][r] * aS[0] + acc[i][1][r] * aS[1] +
                 acc[i][2][r] * aS[2] + acc[i][3][r] * aS[3];
      float pd = acc[i][0][r] * aD[0] + acc[i][1][r] * aD[1] +
                 acc[i][2][r] * aD[2] + acc[i][3][r] * aD[3];
#pragma unroll
      for (int o = 1; o < 16; o <<= 1) {
        ps += __shfl_xor(ps, o, 64);
        pd += __shfl_xor(pd, o, 64);
      }
      int grow = r0 + wm * 64 + i * 16 + q * 4 + r;
      if (mrow == 0 && grow < M) {
        asrc_o[grow * HEADS + hd] = ps;
        adst_o[grow * HEADS + hd] = pd;
      }
    }
  }

  // ---- bf16 C store (C/D layout: col=lane&15, row=(lane>>4)*4+reg) ----
#pragma unroll
  for (int i = 0; i < 4; ++i) {
#pragma unroll
    for (int j = 0; j < 4; ++j) {
      int col = c0 + wn * 64 + j * 16 + mrow;
#pragma unroll
      for (int r = 0; r < 4; ++r) {
        int grow = r0 + wm * 64 + i * 16 + q * 4 + r;
        if (grow < M) Cb[(size_t)grow * HC + col] = f2bf(acc[i][j][r]);
      }
    }
  }
}

__device__ __forceinline__ float lrelu(float x) { return x > 0.f ? x : NEG_SLOPE * x; }

// ---------------- segment softmax + aggregation: ONE WAVE PER NODE ----------------
// Gather phase: half-wave per edge (16B/lane, 2 edges per wave-iteration).
__global__ __launch_bounds__(256) void aggregate_kernel(
    const ush* __restrict__ hbf, const float* __restrict__ asrc,
    const float* __restrict__ adst, const int* __restrict__ row_ptr,
    const int* __restrict__ srcs, const float* __restrict__ bias,
    float* __restrict__ outf, ush* __restrict__ outh, ush* __restrict__ outl, int N) {
  __shared__ float s_alpha[4][64 * 4];
  __shared__ int s_src[4][64];

  int wave = threadIdx.x >> 6;
  int lane = threadIdx.x & 63;
  int node = blockIdx.x * 4 + wave;
  if (node >= N) return;

  int begin = row_ptr[node];
  int end = row_ptr[node + 1];
  int deg = end - begin;
  int nb = deg < 64 ? deg : 64;

  const float4* asrc4 = (const float4*)asrc;
  float4 ad = ((const float4*)adst)[node];

  const float NEGINF = -3.402823466e38f;
  int s0 = 0;
  float4 e0 = make_float4(NEGINF, NEGINF, NEGINF, NEGINF);
  if (lane < nb) {
    s0 = srcs[begin + lane];
    float4 a = asrc4[s0];
    e0.x = lrelu(a.x + ad.x);
    e0.y = lrelu(a.y + ad.y);
    e0.z = lrelu(a.z + ad.z);
    e0.w = lrelu(a.w + ad.w);
  }
  float m0 = e0.x, m1 = e0.y, m2 = e0.z, m3 = e0.w;
  for (int base = 64; base < deg; base += 64) {
    int idx = base + lane;
    if (idx < deg) {
      int s = srcs[begin + idx];
      float4 a = asrc4[s];
      m0 = fmaxf(m0, lrelu(a.x + ad.x));
      m1 = fmaxf(m1, lrelu(a.y + ad.y));
      m2 = fmaxf(m2, lrelu(a.z + ad.z));
      m3 = fmaxf(m3, lrelu(a.w + ad.w));
    }
  }
#pragma unroll
  for (int o = 1; o < 64; o <<= 1) {
    m0 = fmaxf(m0, __shfl_xor(m0, o, 64));
    m1 = fmaxf(m1, __shfl_xor(m1, o, 64));
    m2 = fmaxf(m2, __shfl_xor(m2, o, 64));
    m3 = fmaxf(m3, __shfl_xor(m3, o, 64));
  }
  float ex0 = (lane < nb) ? __expf(e0.x - m0) : 0.f;
  float ex1 = (lane < nb) ? __expf(e0.y - m1) : 0.f;
  float ex2 = (lane < nb) ? __expf(e0.z - m2) : 0.f;
  float ex3 = (lane < nb) ? __expf(e0.w - m3) : 0.f;
  float d0 = ex0, d1 = ex1, d2 = ex2, d3 = ex3;
  for (int base = 64; base < deg; base += 64) {
    int idx = base + lane;
    if (idx < deg) {
      int s = srcs[begin + idx];
      float4 a = asrc4[s];
      d0 += __expf(lrelu(a.x + ad.x) - m0);
      d1 += __expf(lrelu(a.y + ad.y) - m1);
      d2 += __expf(lrelu(a.z + ad.z) - m2);
      d3 += __expf(lrelu(a.w + ad.w) - m3);
    }
  }
#pragma unroll
  for (int o = 1; o < 64; o <<= 1) {
    d0 += __shfl_xor(d0, o, 64);
    d1 += __shfl_xor(d1, o, 64);
    d2 += __shfl_xor(d2, o, 64);
    d3 += __shfl_xor(d3, o, 64);
  }
  float r0 = 1.0f / (d0 + 1e-16f);
  float r1 = 1.0f / (d1 + 1e-16f);
  float r2 = 1.0f / (d2 + 1e-16f);
  float r3 = 1.0f / (d3 + 1e-16f);

  *(float4*)&s_alpha[wave][lane * 4] = make_float4(ex0 * r0, ex1 * r1, ex2 * r2, ex3 * r3);
  s_src[wave][lane] = s0;

  // ---- gather: half-wave per edge; lane owns 8 channels (16B) ----
  int half = lane >> 5;   // 0: even edges, 1: odd edges
  int hl = lane & 31;     // channel block: channels [hl*8, hl*8+8)
  int headh = hl >> 3;    // head of those channels
  float mh = (headh == 0) ? m0 : (headh == 1) ? m1 : (headh == 2) ? m2 : m3;
  float rdh = (headh == 0) ? r0 : (headh == 1) ? r1 : (headh == 2) ? r2 : r3;
  float adh = (headh == 0) ? ad.x : (headh == 1) ? ad.y : (headh == 2) ? ad.z : ad.w;

  const short8* hb8 = (const short8*)hbf;  // row = 32 x short8
  float acc[8];
#pragma unroll
  for (int k = 0; k < 8; ++k) acc[k] = 0.f;

  for (int i = half; i < nb; i += 2) {
    int s = s_src[wave][i];
    float a = s_alpha[wave][i * 4 + headh];
    short8 u = hb8[(size_t)s * 32 + hl];
#pragma unroll
    for (int k = 0; k < 8; ++k) acc[k] += a * bf2f((ush)u[k]);
  }
  // rare: edges beyond 64 — recompute alpha on the fly
  for (int i2 = 64 + half; i2 < deg; i2 += 2) {
    int s = srcs[begin + i2];
    float ash = asrc[s * HEADS + headh];
    float a = __expf(lrelu(ash + adh) - mh) * rdh;
    short8 u = hb8[(size_t)s * 32 + hl];
#pragma unroll
    for (int k = 0; k < 8; ++k) acc[k] += a * bf2f((ush)u[k]);
  }

  // combine even/odd halves
#pragma unroll
  for (int k = 0; k < 8; ++k) acc[k] += __shfl_xor(acc[k], 32, 64);

  if (half == 0) {
    float4 bv0 = ((const float4*)bias)[hl * 2];
    float4 bv1 = ((const float4*)bias)[hl * 2 + 1];
    float o0 = fmaxf(acc[0] + bv0.x, 0.f);
    float o1 = fmaxf(acc[1] + bv0.y, 0.f);
    float o2 = fmaxf(acc[2] + bv0.z, 0.f);
    float o3 = fmaxf(acc[3] + bv0.w, 0.f);
    float o4 = fmaxf(acc[4] + bv1.x, 0.f);
    float o5 = fmaxf(acc[5] + bv1.y, 0.f);
    float o6 = fmaxf(acc[6] + bv1.z, 0.f);
    float o7 = fmaxf(acc[7] + bv1.w, 0.f);
    if (outf) {
      ((float4*)outf)[(size_t)node * 64 + hl * 2] = make_float4(o0, o1, o2, o3);
      ((float4*)outf)[(size_t)node * 64 + hl * 2 + 1] = make_float4(o4, o5, o6, o7);
    } else {
      ush h0 = f2bf(o0), h1 = f2bf(o1), h2 = f2bf(o2), h3 = f2bf(o3);
      ush h4 = f2bf(o4), h5 = f2bf(o5), h6 = f2bf(o6), h7 = f2bf(o7);
      short8 hv;
      hv[0] = (short)h0; hv[1] = (short)h1; hv[2] = (short)h2; hv[3] = (short)h3;
      hv[4] = (short)h4; hv[5] = (short)h5; hv[6] = (short)h6; hv[7] = (short)h7;
      *(short8*)&outh[(size_t)node * HC + hl * 8] = hv;
      if (outl) {
        short8 lv;
        lv[0] = (short)f2bf(o0 - bf2f(h0));
        lv[1] = (short)f2bf(o1 - bf2f(h1));
        lv[2] = (short)f2bf(o2 - bf2f(h2));
        lv[3] = (short)f2bf(o3 - bf2f(h3));
        lv[4] = (short)f2bf(o4 - bf2f(h4));
        lv[5] = (short)f2bf(o5 - bf2f(h5));
        lv[6] = (short)f2bf(o6 - bf2f(h6));
        lv[7] = (short)f2bf(o7 - bf2f(h7));
        *(short8*)&outl[(size_t)node * HC + hl * 8] = lv;
      }
    }
  }
}

// ---------------- global mean pool (batch is sorted, input bf16), 4 partials per graph ----------------
__device__ __forceinline__ int lower_bound_i(const int* a, int n, int key) {
  int lo = 0, hi = n;
  while (lo < hi) {
    int mid = (lo + hi) >> 1;
    if (a[mid] < key) lo = mid + 1; else hi = mid;
  }
  return lo;
}

__global__ __launch_bounds__(256) void pool_kernel(const ush* __restrict__ h2,
                                                   const int* __restrict__ batch,
                                                   float* __restrict__ pws,
                                                   int* __restrict__ cnts, int n) {
  int g = blockIdx.x, part = blockIdx.y;
  int wave = threadIdx.x >> 6, lane = threadIdx.x & 63;
  int lo = lower_bound_i(batch, n, g);
  int hi = lower_bound_i(batch, n, g + 1);
  const ushort4* h4 = (const ushort4*)h2;
  float4 acc = make_float4(0.f, 0.f, 0.f, 0.f);
  for (int i = lo + part * 4 + wave; i < hi; i += 16) {
    ushort4 u = h4[(size_t)i * 64 + lane];
    acc.x += bf2f(u.x); acc.y += bf2f(u.y);
    acc.z += bf2f(u.z); acc.w += bf2f(u.w);
  }
  __shared__ float4 red[4][64];
  red[wave][lane] = acc;
  __syncthreads();
  if (wave == 0) {
    float4 a0 = red[0][lane], a1 = red[1][lane], a2 = red[2][lane], a3 = red[3][lane];
    float4 o;
    o.x = (a0.x + a1.x) + (a2.x + a3.x);
    o.y = (a0.y + a1.y) + (a2.y + a3.y);
    o.z = (a0.z + a1.z) + (a2.z + a3.z);
    o.w = (a0.w + a1.w) + (a2.w + a3.w);
    ((float4*)pws)[(size_t)(g * 4 + part) * 64 + lane] = o;
  }
  if (part == 0 && threadIdx.x == 0) cnts[g] = hi - lo;
}

// ---------------- combine partials + final linear [G,256]@[256,10] ----------------
__global__ void final_kernel(const float* __restrict__ pws, const int* __restrict__ cnts,
                             const float* __restrict__ Wf, const float* __restrict__ bf,
                             float* __restrict__ pooled_out, float* __restrict__ out) {
  int g = blockIdx.x, t = threadIdx.x;
  float s = pws[(size_t)(g * 4 + 0) * 256 + t] + pws[(size_t)(g * 4 + 1) * 256 + t] +
            pws[(size_t)(g * 4 + 2) * 256 + t] + pws[(size_t)(g * 4 + 3) * 256 + t];
  float inv = 1.0f / fmaxf((float)cnts[g], 1.0f);
  float pv = s * inv;
  pooled_out[g * HC + t] = pv;
  __shared__ float p[HC];
  p[t] = pv;
  __syncthreads();
  if (t < 10) {
    float acc = bf[t];
    for (int c = 0; c < HC; ++c) acc += p[c] * Wf[c * 10 + t];
    out[g * 10 + t] = acc;
  }
}

extern "C" void kernel_launch(void* const* d_in, const int* in_sizes, int n_in,
                              void* d_out, int out_size, void* d_ws, size_t ws_size,
                              hipStream_t stream) {
  const float* x    = (const float*)d_in[0];
  const int*   ei   = (const int*)d_in[1];
  const int*   batch = (const int*)d_in[3];
  const float* W1   = (const float*)d_in[4];
  const float* as1  = (const float*)d_in[5];
  const float* ad1  = (const float*)d_in[6];
  const float* b1   = (const float*)d_in[7];
  const float* W2   = (const float*)d_in[8];
  const float* as2  = (const float*)d_in[9];
  const float* ad2  = (const float*)d_in[10];
  const float* b2   = (const float*)d_in[11];
  const float* Wf   = (const float*)d_in[12];
  const float* bf   = (const float*)d_in[13];
  float* out = (float*)d_out;

  const int N = in_sizes[0] / HC;  // 50000
  const int E = in_sizes[1] / 2;   // 800000

  // workspace layout (256B-aligned chunks)
  char* base = (char*)d_ws;
  size_t off = 0;
  auto alloc = [&](size_t bytes) {
    char* p = base + off;
    off = (off + bytes + 255) & ~(size_t)255;
    return p;
  };
  ush* xh = (ush*)alloc((size_t)N * HC * 2);   // bf16 hi (gemm A / agg out)
  ush* xl = (ush*)alloc((size_t)N * HC * 2);   // bf16 lo
  ush* hbf = (ush*)alloc((size_t)N * HC * 2);  // bf16 projected features
  float* asrc = (float*)alloc((size_t)N * HEADS * 4);
  float* adst = (float*)alloc((size_t)N * HEADS * 4);
  int* counts = (int*)alloc((size_t)N * 4);
  int* row_ptr = (int*)alloc((size_t)(N + 1) * 4);
  int* cursor = (int*)alloc((size_t)N * 4);
  int* srcs = (int*)alloc((size_t)(E + N) * 4);
  int* bsums = (int*)alloc(((N + 1023) / 1024) * 4);
  ush* Bth1 = (ush*)alloc((size_t)HC * HC * 2);
  ush* Btl1 = (ush*)alloc((size_t)HC * HC * 2);
  ush* Bth2 = (ush*)alloc((size_t)HC * HC * 2);
  ush* Btl2 = (ush*)alloc((size_t)HC * HC * 2);
  float* pws = (float*)alloc((size_t)GG * 4 * HC * 4);
  int* cnts = (int*)alloc((size_t)GG * 4);

  int nb = (N + 1023) / 1024;

  // CSR build
  hipMemsetAsync(counts, 0, (size_t)N * 4, stream);
  hist_kernel<<<(E + N + 255) / 256, 256, 0, stream>>>(ei, counts, E, N);
  scan_pass1<<<nb, 256, 0, stream>>>(counts, bsums, N);
  scan_pass2<<<1, 256, 0, stream>>>(bsums, row_ptr, nb, N);
  scan_pass3<<<nb, 256, 0, stream>>>(counts, bsums, row_ptr, cursor, N);
  scatter_kernel<<<(E + N + 255) / 256, 256, 0, stream>>>(ei, cursor, srcs, E, N);

  // weight prep + x split
  dim3 cbgrid(HC, 2);
  convertB_kernel<<<cbgrid, HC, 0, stream>>>(W1, W2, Bth1, Btl1, Bth2, Btl2);
  splitA_kernel<<<(N * HC / 4 + 255) / 256, 256, 0, stream>>>(x, xh, xl, N * HC);

  dim3 ggrid(2, (N + 127) / 128);
  int agg_blocks = (N + 3) / 4;

  // layer 1 (aggregate emits bf16 hi/lo for layer-2 GEMM)
  gemm_kernel<<<ggrid, 256, 0, stream>>>(xh, xl, Bth1, Btl1, as1, ad1, hbf, asrc, adst, N);
  aggregate_kernel<<<agg_blocks, 256, 0, stream>>>(hbf, asrc, adst, row_ptr, srcs, b1,
                                                   nullptr, xh, xl, N);

  // layer 2 (aggregate emits bf16 for pooling)
  gemm_kernel<<<ggrid, 256, 0, stream>>>(xh, xl, Bth2, Btl2, as2, ad2, hbf, asrc, adst, N);
  aggregate_kernel<<<agg_blocks, 256, 0, stream>>>(hbf, asrc, adst, row_ptr, srcs, b2,
                                                   nullptr, xh, nullptr, N);

  // pooling + classifier
  dim3 pgrid(GG, 4);
  pool_kernel<<<pgrid, 256, 0, stream>>>(xh, batch, pws, cnts, N);
  final_kernel<<<GG, 256, 0, stream>>>(pws, cnts, Wf, bf, out + GG * 10, out);
}

// Round 11
// 465.696 us; speedup vs baseline: 1.0909x; 1.0169x over previous
//
#include <hip/hip_runtime.h>
#include <math.h>

#define HEADS 4
#define HID 64
#define HC 256
#define NEG_SLOPE 0.2f
#define GG 128

typedef __attribute__((ext_vector_type(8))) short short8;
typedef __attribute__((ext_vector_type(4))) float floatx4;
typedef unsigned short ush;

__device__ __forceinline__ ush f2bf(float f) {
  unsigned u = __float_as_uint(f);
  unsigned r = (u + 0x7FFFu + ((u >> 16) & 1u)) >> 16;  // RNE
  return (ush)r;
}
__device__ __forceinline__ float bf2f(ush h) {
  return __uint_as_float(((unsigned)h) << 16);
}

// ---------------- CSR build (counting sort by dst) ----------------
// counts zeroed by memset; self-loop (+1 per node) folded into the scan passes.
__global__ void hist_kernel(const int* __restrict__ ei, int* counts, int E) {
  int i = blockIdx.x * 256 + threadIdx.x;
  if (i < E) atomicAdd(&counts[ei[E + i]], 1);
}

__global__ __launch_bounds__(256) void scan_pass1(const int* __restrict__ counts,
                                                  int* __restrict__ bsums, int n) {
  int t = threadIdx.x;
  int i0 = blockIdx.x * 1024 + t * 4;
  int s = 0;
  if (i0 + 3 < n) {
    int4 v = *(const int4*)&counts[i0];
    s = v.x + v.y + v.z + v.w + 4;  // +1 self-loop per node
  } else {
#pragma unroll
    for (int k = 0; k < 4; ++k)
      if (i0 + k < n) s += counts[i0 + k] + 1;
  }
#pragma unroll
  for (int o = 1; o < 64; o <<= 1) s += __shfl_xor(s, o, 64);
  __shared__ int ws[4];
  if ((t & 63) == 0) ws[t >> 6] = s;
  __syncthreads();
  if (t == 0) bsums[blockIdx.x] = ws[0] + ws[1] + ws[2] + ws[3];
}

__global__ __launch_bounds__(256) void scan_pass2(int* __restrict__ bsums,
                                                  int* __restrict__ row_ptr, int nb, int n) {
  __shared__ int sh[256];
  int t = threadIdx.x;
  int v = (t < nb) ? bsums[t] : 0;
  sh[t] = v;
  __syncthreads();
  for (int off = 1; off < 256; off <<= 1) {
    int u = (t >= off) ? sh[t - off] : 0;
    __syncthreads();
    sh[t] += u;
    __syncthreads();
  }
  if (t < nb) bsums[t] = sh[t] - v;  // exclusive
  if (t == 255) row_ptr[n] = sh[255];
}

__global__ __launch_bounds__(256) void scan_pass3(const int* __restrict__ counts,
                                                  const int* __restrict__ bsums,
                                                  int* __restrict__ row_ptr,
                                                  int* __restrict__ cursor, int n) {
  int t = threadIdx.x;
  int i0 = blockIdx.x * 1024 + t * 4;
  int c0 = 0, c1 = 0, c2 = 0, c3 = 0;
  bool full = (i0 + 3 < n);
  if (full) {
    int4 v = *(const int4*)&counts[i0];
    c0 = v.x + 1; c1 = v.y + 1; c2 = v.z + 1; c3 = v.w + 1;  // +1 self-loop
  } else {
    if (i0 + 0 < n) c0 = counts[i0 + 0] + 1;
    if (i0 + 1 < n) c1 = counts[i0 + 1] + 1;
    if (i0 + 2 < n) c2 = counts[i0 + 2] + 1;
    if (i0 + 3 < n) c3 = counts[i0 + 3] + 1;
  }
  int ts = c0 + c1 + c2 + c3;
  __shared__ int sh[256];
  sh[t] = ts;
  __syncthreads();
  for (int off = 1; off < 256; off <<= 1) {
    int u = (t >= off) ? sh[t - off] : 0;
    __syncthreads();
    sh[t] += u;
    __syncthreads();
  }
  int run = bsums[blockIdx.x] + sh[t] - ts;
  int r0 = run, r1 = run + c0, r2 = r1 + c1, r3 = r2 + c2;
  if (full) {
    *(int4*)&row_ptr[i0] = make_int4(r0, r1, r2, r3);
    *(int4*)&cursor[i0] = make_int4(r0, r1, r2, r3);
  } else {
    if (i0 + 0 < n) { row_ptr[i0 + 0] = r0; cursor[i0 + 0] = r0; }
    if (i0 + 1 < n) { row_ptr[i0 + 1] = r1; cursor[i0 + 1] = r1; }
    if (i0 + 2 < n) { row_ptr[i0 + 2] = r2; cursor[i0 + 2] = r2; }
    if (i0 + 3 < n) { row_ptr[i0 + 3] = r3; cursor[i0 + 3] = r3; }
  }
}

__global__ void scatter_kernel(const int* __restrict__ ei, int* cursor, int* srcs, int E, int n) {
  int i = blockIdx.x * 256 + threadIdx.x;
  if (i >= E + n) return;
  int s, d;
  if (i < E) { s = ei[i]; d = ei[E + i]; }
  else       { s = i - E; d = s; }
  int pos = atomicAdd(&cursor[d], 1);
  srcs[pos] = s;
}

// ---------------- fp32 -> bf16 hi/lo split (elementwise) ----------------
__global__ __launch_bounds__(256) void splitA_kernel(const float* __restrict__ A,
                                                     ush* __restrict__ Ah,
                                                     ush* __restrict__ Al, int total) {
  int i0 = (blockIdx.x * 256 + threadIdx.x) * 4;
  if (i0 + 3 < total) {
    float4 v = *(const float4*)&A[i0];
    ushort4 h = make_ushort4(f2bf(v.x), f2bf(v.y), f2bf(v.z), f2bf(v.w));
    ushort4 l = make_ushort4(f2bf(v.x - bf2f(h.x)), f2bf(v.y - bf2f(h.y)),
                             f2bf(v.z - bf2f(h.z)), f2bf(v.w - bf2f(h.w)));
    *(ushort4*)&Ah[i0] = h;
    *(ushort4*)&Al[i0] = l;
  } else {
    for (int k = 0; k < 4 && i0 + k < total; ++k) {
      float v = A[i0 + k];
      ush h = f2bf(v);
      Ah[i0 + k] = h;
      Al[i0 + k] = f2bf(v - bf2f(h));
    }
  }
}

// ---------------- both B matrices: fp32 [256,256] -> bf16 hi/lo TRANSPOSED [n][k] ----------------
__global__ void convertB_kernel(const float* __restrict__ W1, const float* __restrict__ W2,
                                ush* __restrict__ Bth1, ush* __restrict__ Btl1,
                                ush* __restrict__ Bth2, ush* __restrict__ Btl2) {
  int k = blockIdx.x, n = threadIdx.x;
  const float* B = blockIdx.y ? W2 : W1;
  ush* th = blockIdx.y ? Bth2 : Bth1;
  ush* tl = blockIdx.y ? Btl2 : Btl1;
  float v = B[k * HC + n];
  ush h = f2bf(v);
  ush l = f2bf(v - bf2f(h));
  th[n * HC + k] = h;
  tl[n * HC + k] = l;
}

// ---------------- bf16-split MFMA GEMM (128x128, reg-prefetched K-loop) ----------------
// grid (2, ceil(M/128)), block 256 (4 waves, 2x2 of 64x64) — R8 shape + 3 waves/EU bound.
#define LDA 40  // padded k-stride in shorts (80B)
__global__ __launch_bounds__(256, 3) void gemm_kernel(
    const ush* __restrict__ Ah, const ush* __restrict__ Al,
    const ush* __restrict__ Bth, const ush* __restrict__ Btl,
    const float* __restrict__ att_src, const float* __restrict__ att_dst,
    ush* __restrict__ Cb, float* __restrict__ asrc_o, float* __restrict__ adst_o, int M) {
  __shared__ ush sAh[128 * LDA];
  __shared__ ush sAl[128 * LDA];
  __shared__ ush sBh[128 * LDA];
  __shared__ ush sBl[128 * LDA];

  int t = threadIdx.x;
  int lane = t & 63, wave = t >> 6;
  int wm = wave >> 1, wn = wave & 1;
  int q = lane >> 4, mrow = lane & 15;
  int r0 = blockIdx.y * 128;
  int c0 = blockIdx.x * 128;
  const int4 zero4 = make_int4(0, 0, 0, 0);

  // staging tasks: 512 (row,seg8) pairs per array -> thread does t and t+256
  int row0 = t >> 2, seg0 = t & 3;
  int row1 = (t + 256) >> 2, seg1 = (t + 256) & 3;
  bool v0 = (r0 + row0) < M, v1 = (r0 + row1) < M;

  const ush* Ag0 = Ah + (size_t)(r0 + row0) * HC + seg0 * 8;
  const ush* Ag1 = Ah + (size_t)(r0 + row1) * HC + seg1 * 8;
  const ush* Al0 = Al + (size_t)(r0 + row0) * HC + seg0 * 8;
  const ush* Al1 = Al + (size_t)(r0 + row1) * HC + seg1 * 8;
  const ush* Bg0 = Bth + (size_t)(c0 + row0) * HC + seg0 * 8;
  const ush* Bg1 = Bth + (size_t)(c0 + row1) * HC + seg1 * 8;
  const ush* Bl0 = Btl + (size_t)(c0 + row0) * HC + seg0 * 8;
  const ush* Bl1 = Btl + (size_t)(c0 + row1) * HC + seg1 * 8;

  int4 pAh0, pAh1, pAl0, pAl1, pBh0, pBh1, pBl0, pBl1;
  // prefetch k0 = 0
  pAh0 = v0 ? *(const int4*)(Ag0) : zero4;
  pAh1 = v1 ? *(const int4*)(Ag1) : zero4;
  pAl0 = v0 ? *(const int4*)(Al0) : zero4;
  pAl1 = v1 ? *(const int4*)(Al1) : zero4;
  pBh0 = *(const int4*)(Bg0);
  pBh1 = *(const int4*)(Bg1);
  pBl0 = *(const int4*)(Bl0);
  pBl1 = *(const int4*)(Bl1);

  floatx4 acc[4][4];
#pragma unroll
  for (int i = 0; i < 4; ++i)
#pragma unroll
    for (int j = 0; j < 4; ++j) acc[i][j] = (floatx4)(0.0f);

  for (int k0 = 0; k0 < HC; k0 += 32) {
    // write prefetched tile to LDS
    *(int4*)&sAh[row0 * LDA + seg0 * 8] = pAh0;
    *(int4*)&sAh[row1 * LDA + seg1 * 8] = pAh1;
    *(int4*)&sAl[row0 * LDA + seg0 * 8] = pAl0;
    *(int4*)&sAl[row1 * LDA + seg1 * 8] = pAl1;
    *(int4*)&sBh[row0 * LDA + seg0 * 8] = pBh0;
    *(int4*)&sBh[row1 * LDA + seg1 * 8] = pBh1;
    *(int4*)&sBl[row0 * LDA + seg0 * 8] = pBl0;
    *(int4*)&sBl[row1 * LDA + seg1 * 8] = pBl1;
    __syncthreads();

    // issue next iteration's global loads (latency overlaps MFMA phase)
    int kn = k0 + 32;
    if (kn < HC) {
      pAh0 = v0 ? *(const int4*)(Ag0 + kn) : zero4;
      pAh1 = v1 ? *(const int4*)(Ag1 + kn) : zero4;
      pAl0 = v0 ? *(const int4*)(Al0 + kn) : zero4;
      pAl1 = v1 ? *(const int4*)(Al1 + kn) : zero4;
      pBh0 = *(const int4*)(Bg0 + kn);
      pBh1 = *(const int4*)(Bg1 + kn);
      pBl0 = *(const int4*)(Bl0 + kn);
      pBl1 = *(const int4*)(Bl1 + kn);
    }

    short8 ah[4], al[4], bh[4], bl[4];
#pragma unroll
    for (int i = 0; i < 4; ++i) {
      int ar = (wm * 64 + i * 16 + mrow) * LDA + q * 8;
      int br = (wn * 64 + i * 16 + mrow) * LDA + q * 8;
      ah[i] = *(short8*)&sAh[ar];
      al[i] = *(short8*)&sAl[ar];
      bh[i] = *(short8*)&sBh[br];
      bl[i] = *(short8*)&sBl[br];
    }
#pragma unroll
    for (int i = 0; i < 4; ++i)
#pragma unroll
      for (int j = 0; j < 4; ++j) {
        acc[i][j] = __builtin_amdgcn_mfma_f32_16x16x32_bf16(ah[i], bh[j], acc[i][j], 0, 0, 0);
        acc[i][j] = __builtin_amdgcn_mfma_f32_16x16x32_bf16(ah[i], bl[j], acc[i][j], 0, 0, 0);
        acc[i][j] = __builtin_amdgcn_mfma_f32_16x16x32_bf16(al[i], bh[j], acc[i][j], 0, 0, 0);
      }
    __syncthreads();
  }

  // ---- fused att: wave wn owns head hd's full 64-col stripe ----
  int hd = (c0 >> 6) + wn;
  float aS[4], aD[4];
#pragma unroll
  for (int j = 0; j < 4; ++j) {
    aS[j] = att_src[hd * 64 + j * 16 + mrow];
    aD[j] = att_dst[hd * 64 + j * 16 + mrow];
  }
#pragma unroll
  for (int i = 0; i < 4; ++i) {
#pragma unroll
    for (int r = 0; r < 4; ++r) {
      float ps = acc[i][0][r] * aS[0] + acc[i][1][r] * aS[1] +
                 acc[i][2][r] * aS[2] + acc[i][3][r] * aS[3];
      float pd = acc[i][0][r] * aD[0] + acc[i][1][r] * aD[1] +
                 acc[i][2][r] * aD[2] + acc[i][3][r] * aD[3];
#pragma unroll
      for (int o = 1; o < 16; o <<= 1) {
        ps += __shfl_xor(ps, o, 64);
        pd += __shfl_xor(pd, o, 64);
      }
      int grow = r0 + wm * 64 + i * 16 + q * 4 + r;
      if (mrow == 0 && grow < M) {
        asrc_o[grow * HEADS + hd] = ps;
        adst_o[grow * HEADS + hd] = pd;
      }
    }
  }

  // ---- bf16 C store (C/D layout: col=lane&15, row=(lane>>4)*4+reg) ----
#pragma unroll
  for (int i = 0; i < 4; ++i) {
#pragma unroll
    for (int j = 0; j < 4; ++j) {
      int col = c0 + wn * 64 + j * 16 + mrow;
#pragma unroll
      for (int r = 0; r < 4; ++r) {
        int grow = r0 + wm * 64 + i * 16 + q * 4 + r;
        if (grow < M) Cb[(size_t)grow * HC + col] = f2bf(acc[i][j][r]);
      }
    }
  }
}

__device__ __forceinline__ float lrelu(float x) { return x > 0.f ? x : NEG_SLOPE * x; }

// ---------------- segment softmax + aggregation: ONE WAVE PER NODE ----------------
// Gather phase: half-wave per edge (16B/lane, 2 edges per wave-iteration).
__global__ __launch_bounds__(256) void aggregate_kernel(
    const ush* __restrict__ hbf, const float* __restrict__ asrc,
    const float* __restrict__ adst, const int* __restrict__ row_ptr,
    const int* __restrict__ srcs, const float* __restrict__ bias,
    float* __restrict__ outf, ush* __restrict__ outh, ush* __restrict__ outl, int N) {
  __shared__ float s_alpha[4][64 * 4];
  __shared__ int s_src[4][64];

  int wave = threadIdx.x >> 6;
  int lane = threadIdx.x & 63;
  int node = blockIdx.x * 4 + wave;
  if (node >= N) return;

  int begin = row_ptr[node];
  int end = row_ptr[node + 1];
  int deg = end - begin;
  int nb = deg < 64 ? deg : 64;

  const float4* asrc4 = (const float4*)asrc;
  float4 ad = ((const float4*)adst)[node];

  const float NEGINF = -3.402823466e38f;
  int s0 = 0;
  float4 e0 = make_float4(NEGINF, NEGINF, NEGINF, NEGINF);
  if (lane < nb) {
    s0 = srcs[begin + lane];
    float4 a = asrc4[s0];
    e0.x = lrelu(a.x + ad.x);
    e0.y = lrelu(a.y + ad.y);
    e0.z = lrelu(a.z + ad.z);
    e0.w = lrelu(a.w + ad.w);
  }
  float m0 = e0.x, m1 = e0.y, m2 = e0.z, m3 = e0.w;
  for (int base = 64; base < deg; base += 64) {
    int idx = base + lane;
    if (idx < deg) {
      int s = srcs[begin + idx];
      float4 a = asrc4[s];
      m0 = fmaxf(m0, lrelu(a.x + ad.x));
      m1 = fmaxf(m1, lrelu(a.y + ad.y));
      m2 = fmaxf(m2, lrelu(a.z + ad.z));
      m3 = fmaxf(m3, lrelu(a.w + ad.w));
    }
  }
#pragma unroll
  for (int o = 1; o < 64; o <<= 1) {
    m0 = fmaxf(m0, __shfl_xor(m0, o, 64));
    m1 = fmaxf(m1, __shfl_xor(m1, o, 64));
    m2 = fmaxf(m2, __shfl_xor(m2, o, 64));
    m3 = fmaxf(m3, __shfl_xor(m3, o, 64));
  }
  float ex0 = (lane < nb) ? __expf(e0.x - m0) : 0.f;
  float ex1 = (lane < nb) ? __expf(e0.y - m1) : 0.f;
  float ex2 = (lane < nb) ? __expf(e0.z - m2) : 0.f;
  float ex3 = (lane < nb) ? __expf(e0.w - m3) : 0.f;
  float d0 = ex0, d1 = ex1, d2 = ex2, d3 = ex3;
  for (int base = 64; base < deg; base += 64) {
    int idx = base + lane;
    if (idx < deg) {
      int s = srcs[begin + idx];
      float4 a = asrc4[s];
      d0 += __expf(lrelu(a.x + ad.x) - m0);
      d1 += __expf(lrelu(a.y + ad.y) - m1);
      d2 += __expf(lrelu(a.z + ad.z) - m2);
      d3 += __expf(lrelu(a.w + ad.w) - m3);
    }
  }
#pragma unroll
  for (int o = 1; o < 64; o <<= 1) {
    d0 += __shfl_xor(d0, o, 64);
    d1 += __shfl_xor(d1, o, 64);
    d2 += __shfl_xor(d2, o, 64);
    d3 += __shfl_xor(d3, o, 64);
  }
  float r0 = 1.0f / (d0 + 1e-16f);
  float r1 = 1.0f / (d1 + 1e-16f);
  float r2 = 1.0f / (d2 + 1e-16f);
  float r3 = 1.0f / (d3 + 1e-16f);

  *(float4*)&s_alpha[wave][lane * 4] = make_float4(ex0 * r0, ex1 * r1, ex2 * r2, ex3 * r3);
  s_src[wave][lane] = s0;

  // ---- gather: half-wave per edge; lane owns 8 channels (16B) ----
  int half = lane >> 5;   // 0: even edges, 1: odd edges
  int hl = lane & 31;     // channel block: channels [hl*8, hl*8+8)
  int headh = hl >> 3;    // head of those channels
  float mh = (headh == 0) ? m0 : (headh == 1) ? m1 : (headh == 2) ? m2 : m3;
  float rdh = (headh == 0) ? r0 : (headh == 1) ? r1 : (headh == 2) ? r2 : r3;
  float adh = (headh == 0) ? ad.x : (headh == 1) ? ad.y : (headh == 2) ? ad.z : ad.w;

  const short8* hb8 = (const short8*)hbf;  // row = 32 x short8
  float acc[8];
#pragma unroll
  for (int k = 0; k < 8; ++k) acc[k] = 0.f;

  for (int i = half; i < nb; i += 2) {
    int s = s_src[wave][i];
    float a = s_alpha[wave][i * 4 + headh];
    short8 u = hb8[(size_t)s * 32 + hl];
#pragma unroll
    for (int k = 0; k < 8; ++k) acc[k] += a * bf2f((ush)u[k]);
  }
  // rare: edges beyond 64 — recompute alpha on the fly
  for (int i2 = 64 + half; i2 < deg; i2 += 2) {
    int s = srcs[begin + i2];
    float ash = asrc[s * HEADS + headh];
    float a = __expf(lrelu(ash + adh) - mh) * rdh;
    short8 u = hb8[(size_t)s * 32 + hl];
#pragma unroll
    for (int k = 0; k < 8; ++k) acc[k] += a * bf2f((ush)u[k]);
  }

  // combine even/odd halves
#pragma unroll
  for (int k = 0; k < 8; ++k) acc[k] += __shfl_xor(acc[k], 32, 64);

  if (half == 0) {
    float4 bv0 = ((const float4*)bias)[hl * 2];
    float4 bv1 = ((const float4*)bias)[hl * 2 + 1];
    float o0 = fmaxf(acc[0] + bv0.x, 0.f);
    float o1 = fmaxf(acc[1] + bv0.y, 0.f);
    float o2 = fmaxf(acc[2] + bv0.z, 0.f);
    float o3 = fmaxf(acc[3] + bv0.w, 0.f);
    float o4 = fmaxf(acc[4] + bv1.x, 0.f);
    float o5 = fmaxf(acc[5] + bv1.y, 0.f);
    float o6 = fmaxf(acc[6] + bv1.z, 0.f);
    float o7 = fmaxf(acc[7] + bv1.w, 0.f);
    if (outf) {
      ((float4*)outf)[(size_t)node * 64 + hl * 2] = make_float4(o0, o1, o2, o3);
      ((float4*)outf)[(size_t)node * 64 + hl * 2 + 1] = make_float4(o4, o5, o6, o7);
    } else {
      ush h0 = f2bf(o0), h1 = f2bf(o1), h2 = f2bf(o2), h3 = f2bf(o3);
      ush h4 = f2bf(o4), h5 = f2bf(o5), h6 = f2bf(o6), h7 = f2bf(o7);
      short8 hv;
      hv[0] = (short)h0; hv[1] = (short)h1; hv[2] = (short)h2; hv[3] = (short)h3;
      hv[4] = (short)h4; hv[5] = (short)h5; hv[6] = (short)h6; hv[7] = (short)h7;
      *(short8*)&outh[(size_t)node * HC + hl * 8] = hv;
      if (outl) {
        short8 lv;
        lv[0] = (short)f2bf(o0 - bf2f(h0));
        lv[1] = (short)f2bf(o1 - bf2f(h1));
        lv[2] = (short)f2bf(o2 - bf2f(h2));
        lv[3] = (short)f2bf(o3 - bf2f(h3));
        lv[4] = (short)f2bf(o4 - bf2f(h4));
        lv[5] = (short)f2bf(o5 - bf2f(h5));
        lv[6] = (short)f2bf(o6 - bf2f(h6));
        lv[7] = (short)f2bf(o7 - bf2f(h7));
        *(short8*)&outl[(size_t)node * HC + hl * 8] = lv;
      }
    }
  }
}

// ---------------- global mean pool (batch is sorted, input bf16), 4 partials per graph ----------------
__device__ __forceinline__ int lower_bound_i(const int* a, int n, int key) {
  int lo = 0, hi = n;
  while (lo < hi) {
    int mid = (lo + hi) >> 1;
    if (a[mid] < key) lo = mid + 1; else hi = mid;
  }
  return lo;
}

__global__ __launch_bounds__(256) void pool_kernel(const ush* __restrict__ h2,
                                                   const int* __restrict__ batch,
                                                   float* __restrict__ pws,
                                                   int* __restrict__ cnts, int n) {
  int g = blockIdx.x, part = blockIdx.y;
  int wave = threadIdx.x >> 6, lane = threadIdx.x & 63;
  int lo = lower_bound_i(batch, n, g);
  int hi = lower_bound_i(batch, n, g + 1);
  const ushort4* h4 = (const ushort4*)h2;
  float4 acc = make_float4(0.f, 0.f, 0.f, 0.f);
  for (int i = lo + part * 4 + wave; i < hi; i += 16) {
    ushort4 u = h4[(size_t)i * 64 + lane];
    acc.x += bf2f(u.x); acc.y += bf2f(u.y);
    acc.z += bf2f(u.z); acc.w += bf2f(u.w);
  }
  __shared__ float4 red[4][64];
  red[wave][lane] = acc;
  __syncthreads();
  if (wave == 0) {
    float4 a0 = red[0][lane], a1 = red[1][lane], a2 = red[2][lane], a3 = red[3][lane];
    float4 o;
    o.x = (a0.x + a1.x) + (a2.x + a3.x);
    o.y = (a0.y + a1.y) + (a2.y + a3.y);
    o.z = (a0.z + a1.z) + (a2.z + a3.z);
    o.w = (a0.w + a1.w) + (a2.w + a3.w);
    ((float4*)pws)[(size_t)(g * 4 + part) * 64 + lane] = o;
  }
  if (part == 0 && threadIdx.x == 0) cnts[g] = hi - lo;
}

// ---------------- combine partials + final linear [G,256]@[256,10] ----------------
__global__ void final_kernel(const float* __restrict__ pws, const int* __restrict__ cnts,
                             const float* __restrict__ Wf, const float* __restrict__ bf,
                             float* __restrict__ pooled_out, float* __restrict__ out) {
  int g = blockIdx.x, t = threadIdx.x;
  float s = pws[(size_t)(g * 4 + 0) * 256 + t] + pws[(size_t)(g * 4 + 1) * 256 + t] +
            pws[(size_t)(g * 4 + 2) * 256 + t] + pws[(size_t)(g * 4 + 3) * 256 + t];
  float inv = 1.0f / fmaxf((float)cnts[g], 1.0f);
  float pv = s * inv;
  pooled_out[g * HC + t] = pv;
  __shared__ float p[HC];
  p[t] = pv;
  __syncthreads();
  if (t < 10) {
    float acc = bf[t];
    for (int c = 0; c < HC; ++c) acc += p[c] * Wf[c * 10 + t];
    out[g * 10 + t] = acc;
  }
}

extern "C" void kernel_launch(void* const* d_in, const int* in_sizes, int n_in,
                              void* d_out, int out_size, void* d_ws, size_t ws_size,
                              hipStream_t stream) {
  const float* x    = (const float*)d_in[0];
  const int*   ei   = (const int*)d_in[1];
  const int*   batch = (const int*)d_in[3];
  const float* W1   = (const float*)d_in[4];
  const float* as1  = (const float*)d_in[5];
  const float* ad1  = (const float*)d_in[6];
  const float* b1   = (const float*)d_in[7];
  const float* W2   = (const float*)d_in[8];
  const float* as2  = (const float*)d_in[9];
  const float* ad2  = (const float*)d_in[10];
  const float* b2   = (const float*)d_in[11];
  const float* Wf   = (const float*)d_in[12];
  const float* bf   = (const float*)d_in[13];
  float* out = (float*)d_out;

  const int N = in_sizes[0] / HC;  // 50000
  const int E = in_sizes[1] / 2;   // 800000

  // workspace layout (256B-aligned chunks)
  char* base = (char*)d_ws;
  size_t off = 0;
  auto alloc = [&](size_t bytes) {
    char* p = base + off;
    off = (off + bytes + 255) & ~(size_t)255;
    return p;
  };
  ush* xh = (ush*)alloc((size_t)N * HC * 2);   // bf16 hi (gemm A / agg out)
  ush* xl = (ush*)alloc((size_t)N * HC * 2);   // bf16 lo
  ush* hbf = (ush*)alloc((size_t)N * HC * 2);  // bf16 projected features
  float* asrc = (float*)alloc((size_t)N * HEADS * 4);
  float* adst = (float*)alloc((size_t)N * HEADS * 4);
  int* counts = (int*)alloc((size_t)N * 4);
  int* row_ptr = (int*)alloc((size_t)(N + 1) * 4);
  int* cursor = (int*)alloc((size_t)N * 4);
  int* srcs = (int*)alloc((size_t)(E + N) * 4);
  int* bsums = (int*)alloc(((N + 1023) / 1024) * 4);
  ush* Bth1 = (ush*)alloc((size_t)HC * HC * 2);
  ush* Btl1 = (ush*)alloc((size_t)HC * HC * 2);
  ush* Bth2 = (ush*)alloc((size_t)HC * HC * 2);
  ush* Btl2 = (ush*)alloc((size_t)HC * HC * 2);
  float* pws = (float*)alloc((size_t)GG * 4 * HC * 4);
  int* cnts = (int*)alloc((size_t)GG * 4);

  int nb = (N + 1023) / 1024;

  // CSR build (self-loops folded into scans)
  hipMemsetAsync(counts, 0, (size_t)N * 4, stream);
  hist_kernel<<<(E + 255) / 256, 256, 0, stream>>>(ei, counts, E);
  scan_pass1<<<nb, 256, 0, stream>>>(counts, bsums, N);
  scan_pass2<<<1, 256, 0, stream>>>(bsums, row_ptr, nb, N);
  scan_pass3<<<nb, 256, 0, stream>>>(counts, bsums, row_ptr, cursor, N);
  scatter_kernel<<<(E + N + 255) / 256, 256, 0, stream>>>(ei, cursor, srcs, E, N);

  // weight prep + x split
  dim3 cbgrid(HC, 2);
  convertB_kernel<<<cbgrid, HC, 0, stream>>>(W1, W2, Bth1, Btl1, Bth2, Btl2);
  splitA_kernel<<<(N * HC / 4 + 255) / 256, 256, 0, stream>>>(x, xh, xl, N * HC);

  dim3 ggrid(2, (N + 127) / 128);
  int agg_blocks = (N + 3) / 4;

  // layer 1 (aggregate emits bf16 hi/lo for layer-2 GEMM)
  gemm_kernel<<<ggrid, 256, 0, stream>>>(xh, xl, Bth1, Btl1, as1, ad1, hbf, asrc, adst, N);
  aggregate_kernel<<<agg_blocks, 256, 0, stream>>>(hbf, asrc, adst, row_ptr, srcs, b1,
                                                   nullptr, xh, xl, N);

  // layer 2 (aggregate emits bf16 for pooling)
  gemm_kernel<<<ggrid, 256, 0, stream>>>(xh, xl, Bth2, Btl2, as2, ad2, hbf, asrc, adst, N);
  aggregate_kernel<<<agg_blocks, 256, 0, stream>>>(hbf, asrc, adst, row_ptr, srcs, b2,
                                                   nullptr, xh, nullptr, N);

  // pooling + classifier
  dim3 pgrid(GG, 4);
  pool_kernel<<<pgrid, 256, 0, stream>>>(xh, batch, pws, cnts, N);
  final_kernel<<<GG, 256, 0, stream>>>(pws, cnts, Wf, bf, out + GG * 10, out);
}